// Round 4
// baseline (2441.696 us; speedup 1.0000x reference)
//
#include <hip/hip_runtime.h>

#define N_NODES 50000
#define N_EDGES 500000
#define EMB 50
#define HID 64
#define OUTD 50
#define EDIM 28
#define HEADS 4
#define F1 256              // HEADS*HID
#define NEG 0.2f
#define EPS_SM 1e-16f
#define EPS_LN 1e-5f

typedef unsigned short u16;
typedef unsigned int u32;

__device__ __forceinline__ float b2f(u16 u) { return __uint_as_float(((u32)u) << 16); }
__device__ __forceinline__ u16 f2b(float f) {
    u32 u = __float_as_uint(f);
    u32 r = (u + 0x7FFFu + ((u >> 16) & 1u)) >> 16;
    return (u16)r;
}
__device__ __forceinline__ float lrelu(float x) { return x > 0.f ? x : NEG * x; }

// ======================= CSR build =======================
__global__ void k_hist(const int* __restrict__ dst, int* __restrict__ cnt) {
    int e = blockIdx.x * blockDim.x + threadIdx.x;
    if (e < N_EDGES) atomicAdd(&cnt[dst[e]], 1);
}

__global__ __launch_bounds__(1024) void k_scan(const int* __restrict__ cnt, int* __restrict__ rowptr) {
    __shared__ int part[1024];
    int tid = threadIdx.x;
    const int CH = (N_NODES + 1023) / 1024;   // 49
    int beg = tid * CH;
    int end = beg + CH; if (end > N_NODES) end = N_NODES;
    int s = 0;
    for (int i = beg; i < end && i >= beg; i++) s += cnt[i];
    part[tid] = s;
    __syncthreads();
    for (int off = 1; off < 1024; off <<= 1) {
        int v = (tid >= off) ? part[tid - off] : 0;
        __syncthreads();
        part[tid] += v;
        __syncthreads();
    }
    int run = (tid == 0) ? 0 : part[tid - 1];
    for (int i = beg; i < end && i >= beg; i++) { rowptr[i] = run; run += cnt[i]; }
    if (tid == 1023) rowptr[N_NODES] = run;
}

__global__ void k_scatter(const int* __restrict__ src, const int* __restrict__ dst,
                          const int* __restrict__ rowptr, int* __restrict__ cursor,
                          int* __restrict__ eid, int* __restrict__ esrc) {
    int e = blockIdx.x * blockDim.x + threadIdx.x;
    if (e >= N_EDGES) return;
    int d = dst[e];
    int pos = atomicAdd(&cursor[d], 1);
    int slot = rowptr[d] + pos;
    eid[slot]  = e;
    esrc[slot] = src[e];
}

// ======================= conv1 node transform =======================
// xl/xr = emb[x[n]] @ Wl/Wr + b; 8 nodes per tile, weights bf16 in LDS, outputs bf16
#define NT1 8
__global__ __launch_bounds__(256) void k_node1(
    const int* __restrict__ x, const float* __restrict__ emb,
    const float* __restrict__ Wl, const float* __restrict__ bl,
    const float* __restrict__ Wr, const float* __restrict__ br,
    u16* __restrict__ xl, u16* __restrict__ xr)
{
    __shared__ u16 wls[EMB * F1];
    __shared__ u16 wrs[EMB * F1];
    __shared__ float h0s[NT1 * EMB];
    __shared__ int xs[NT1];
    int tid = threadIdx.x;
    for (int i = tid; i < EMB * F1; i += 256) { wls[i] = f2b(Wl[i]); wrs[i] = f2b(Wr[i]); }
    float blr = bl[tid], brr = br[tid];
    __syncthreads();
    const int ntiles = N_NODES / NT1;   // 6250
    for (int tile = blockIdx.x; tile < ntiles; tile += gridDim.x) {
        int nb = tile * NT1;
        if (tid < NT1) xs[tid] = x[nb + tid];
        __syncthreads();
        for (int i = tid; i < NT1 * EMB; i += 256) {
            int nn = i / EMB, k = i - nn * EMB;
            h0s[i] = emb[(size_t)xs[nn] * EMB + k];
        }
        __syncthreads();
        float accl[NT1], accr[NT1];
        #pragma unroll
        for (int n = 0; n < NT1; n++) { accl[n] = blr; accr[n] = brr; }
        for (int k = 0; k < EMB; k++) {
            float wl_ = b2f(wls[k * F1 + tid]);
            float wr_ = b2f(wrs[k * F1 + tid]);
            #pragma unroll
            for (int n = 0; n < NT1; n++) {
                float h = h0s[n * EMB + k];
                accl[n] += h * wl_;
                accr[n] += h * wr_;
            }
        }
        #pragma unroll
        for (int n = 0; n < NT1; n++) {
            xl[(size_t)(nb + n) * F1 + tid] = f2b(accl[n]);
            xr[(size_t)(nb + n) * F1 + tid] = f2b(accr[n]);
        }
        __syncthreads();
    }
}

// ======================= conv1 edge logits =======================
// thread = feature column c (= tid); We column in registers; wave w == head w.
__global__ __launch_bounds__(256) void k_edge1(
    const int* __restrict__ srcA, const int* __restrict__ dstA,
    const float* __restrict__ ea, const u16* __restrict__ xl, const u16* __restrict__ xr,
    const float* __restrict__ We, const float* __restrict__ att,
    float* __restrict__ logits)
{
    __shared__ float eas[64 * EDIM];
    __shared__ int ss[64], dd[64];
    int tid = threadIdx.x;
    int w = tid >> 6, lane = tid & 63;
    float weR[EDIM];
    #pragma unroll
    for (int k = 0; k < EDIM; k++) weR[k] = We[k * F1 + tid];
    float attR = att[tid];
    int base = blockIdx.x * 64;
    int ne = N_EDGES - base; if (ne > 64) ne = 64;
    for (int i = tid; i < ne * EDIM; i += 256) eas[i] = ea[(size_t)base * EDIM + i];
    if (tid < ne) { ss[tid] = srcA[base + tid]; dd[tid] = dstA[base + tid]; }
    __syncthreads();
    #pragma unroll 2
    for (int e0 = 0; e0 < ne; e0++) {
        const float* er = eas + e0 * EDIM;
        float a0 = 0, a1 = 0, a2 = 0, a3 = 0;
        #pragma unroll
        for (int k = 0; k < EDIM; k += 4) {
            a0 += er[k]     * weR[k];
            a1 += er[k + 1] * weR[k + 1];
            a2 += er[k + 2] * weR[k + 2];
            a3 += er[k + 3] * weR[k + 3];
        }
        float xe = (a0 + a1) + (a2 + a3);
        int s = ss[e0], d = dd[e0];
        float v = lrelu(b2f(xl[(size_t)s * F1 + tid]) + b2f(xr[(size_t)d * F1 + tid]) + xe) * attR;
        #pragma unroll
        for (int off = 32; off; off >>= 1) v += __shfl_xor(v, off);
        if (lane == 0) logits[(size_t)(base + e0) * 4 + w] = v;
    }
}

// ======================= conv1 aggregate + bias + LN stats =======================
// one wave per (node, head); CSR edges; no atomics on out.
__global__ __launch_bounds__(256) void k_agg1(
    const int* __restrict__ rowptr, const int* __restrict__ esrc, const int* __restrict__ eid,
    const float* __restrict__ logits, const u16* __restrict__ xl, const float* __restrict__ bias,
    float* __restrict__ out, float* __restrict__ S)
{
    int node = blockIdx.x;
    int h = threadIdx.x >> 6, lane = threadIdx.x & 63;
    int beg = rowptr[node], end = rowptr[node + 1];
    float m = -1e30f;
    for (int j = beg + lane; j < end; j += 64) m = fmaxf(m, logits[(size_t)eid[j] * 4 + h]);
    #pragma unroll
    for (int off = 32; off; off >>= 1) m = fmaxf(m, __shfl_xor(m, off));
    float acc = 0.f, dtot = 0.f;
    for (int b = beg; b < end; b += 64) {
        int j = b + lane;
        bool act = j < end;
        int e_ = act ? eid[j] : 0;
        int sR = act ? esrc[j] : 0;
        float ex = act ? expf(logits[(size_t)e_ * 4 + h] - m) : 0.f;
        float bs = ex;
        #pragma unroll
        for (int off = 32; off; off >>= 1) bs += __shfl_xor(bs, off);
        dtot += bs;
        int cnt = end - b; if (cnt > 64) cnt = 64;
        #pragma unroll 4
        for (int t = 0; t < cnt; t++) {
            float wgt = __shfl(ex, t);
            int s = __shfl(sR, t);
            acc += wgt * b2f(xl[(size_t)s * F1 + (h << 6) + lane]);
        }
    }
    float o = ((end > beg) ? acc / (dtot + EPS_SM) : 0.f) + bias[(h << 6) + lane];
    out[(size_t)node * F1 + (h << 6) + lane] = o;
    // LN statistics
    float s1 = o, s2 = o * o;
    #pragma unroll
    for (int off = 32; off; off >>= 1) { s1 += __shfl_xor(s1, off); s2 += __shfl_xor(s2, off); }
    __shared__ float ls1[4], ls2[4];
    if (lane == 0) { ls1[h] = s1; ls2[h] = s2; }
    __syncthreads();
    if (threadIdx.x == 0) {
        atomicAdd(S,     ls1[0] + ls1[1] + ls1[2] + ls1[3]);
        atomicAdd(S + 1, ls2[0] + ls2[1] + ls2[2] + ls2[3]);
    }
}

// ======================= LayerNorm apply (+ReLU) — bias already folded in =======================
__global__ void k_ln_apply_relu(
    float* v, const float* __restrict__ w, const float* __restrict__ b,
    const float* __restrict__ S, int M, int C)
{
    int i = blockIdx.x * blockDim.x + threadIdx.x;
    if (i >= M) return;
    float mu = S[0] / (float)M;
    float var = S[1] / (float)M - mu * mu;
    float inv = 1.f / (sqrtf(fmaxf(var, 0.f)) + EPS_LN);
    int c = i % C;
    float y = (v[i] - mu) * inv * w[c] + b[c];
    v[i] = fmaxf(y, 0.f);
}

__global__ void k_ln_out(
    const float* __restrict__ v, const float* __restrict__ w, const float* __restrict__ b,
    const float* __restrict__ S, int M, int C, float* __restrict__ out)
{
    int i = blockIdx.x * blockDim.x + threadIdx.x;
    if (i >= M) return;
    float mu = S[0] / (float)M;
    float var = S[1] / (float)M - mu * mu;
    float inv = 1.f / (sqrtf(fmaxf(var, 0.f)) + EPS_LN);
    int c = i % C;
    out[i] = (v[i] - mu) * inv * w[c] + b[c];
}

// ======================= conv2 node transform =======================
// 16 nodes per tile; wave w handles 4 nodes; lane = output col (<50)
#define NT2 16
__global__ __launch_bounds__(256) void k_node2(
    const float* __restrict__ h, const float* __restrict__ Wl, const float* __restrict__ bl,
    const float* __restrict__ Wr, const float* __restrict__ br,
    float* __restrict__ xl, float* __restrict__ xr)
{
    __shared__ u16 wls[F1 * OUTD];
    __shared__ u16 wrs[F1 * OUTD];
    __shared__ float hs[NT2 * F1];
    int tid = threadIdx.x;
    int w = tid >> 6, lane = tid & 63;
    for (int i = tid; i < F1 * OUTD; i += 256) { wls[i] = f2b(Wl[i]); wrs[i] = f2b(Wr[i]); }
    float blr = (lane < OUTD) ? bl[lane] : 0.f;
    float brr = (lane < OUTD) ? br[lane] : 0.f;
    __syncthreads();
    const int ntiles = N_NODES / NT2;   // 3125
    for (int tile = blockIdx.x; tile < ntiles; tile += gridDim.x) {
        int nb = tile * NT2;
        for (int i = tid; i < NT2 * F1; i += 256) hs[i] = h[(size_t)nb * F1 + i];
        __syncthreads();
        if (lane < OUTD) {
            float accl[4] = {blr, blr, blr, blr};
            float accr[4] = {brr, brr, brr, brr};
            int nl = w * 4;
            for (int k = 0; k < F1; k++) {
                float wl_ = b2f(wls[k * OUTD + lane]);
                float wr_ = b2f(wrs[k * OUTD + lane]);
                #pragma unroll
                for (int n = 0; n < 4; n++) {
                    float hv = hs[(nl + n) * F1 + k];
                    accl[n] += hv * wl_;
                    accr[n] += hv * wr_;
                }
            }
            #pragma unroll
            for (int n = 0; n < 4; n++) {
                xl[(size_t)(nb + nl + n) * OUTD + lane] = accl[n];
                xr[(size_t)(nb + nl + n) * OUTD + lane] = accr[n];
            }
        }
        __syncthreads();
    }
}

// ======================= conv2 edge logits =======================
__global__ __launch_bounds__(256) void k_edge2(
    const int* __restrict__ srcA, const int* __restrict__ dstA,
    const float* __restrict__ ea, const float* __restrict__ xl, const float* __restrict__ xr,
    const float* __restrict__ We, const float* __restrict__ att,
    float* __restrict__ logits)
{
    __shared__ float eas[64 * EDIM];
    __shared__ int ss[64], dd[64];
    int tid = threadIdx.x;
    int w = tid >> 6, lane = tid & 63;
    float weR[EDIM];
    float attR = 0.f;
    if (lane < OUTD) {
        #pragma unroll
        for (int k = 0; k < EDIM; k++) weR[k] = We[k * OUTD + lane];
        attR = att[lane];
    } else {
        #pragma unroll
        for (int k = 0; k < EDIM; k++) weR[k] = 0.f;
    }
    int base = blockIdx.x * 64;
    int ne = N_EDGES - base; if (ne > 64) ne = 64;
    for (int i = tid; i < ne * EDIM; i += 256) eas[i] = ea[(size_t)base * EDIM + i];
    if (tid < ne) { ss[tid] = srcA[base + tid]; dd[tid] = dstA[base + tid]; }
    __syncthreads();
    for (int t = 0; t < 16; t++) {
        int e0 = (w << 4) + t;
        if (e0 >= ne) break;
        const float* er = eas + e0 * EDIM;
        float a0 = 0, a1 = 0, a2 = 0, a3 = 0;
        #pragma unroll
        for (int k = 0; k < EDIM; k += 4) {
            a0 += er[k]     * weR[k];
            a1 += er[k + 1] * weR[k + 1];
            a2 += er[k + 2] * weR[k + 2];
            a3 += er[k + 3] * weR[k + 3];
        }
        float xe = (a0 + a1) + (a2 + a3);
        int s = ss[e0], d = dd[e0];
        float v = 0.f;
        if (lane < OUTD)
            v = lrelu(xl[(size_t)s * OUTD + lane] + xr[(size_t)d * OUTD + lane] + xe) * attR;
        #pragma unroll
        for (int off = 32; off; off >>= 1) v += __shfl_xor(v, off);
        if (lane == 0) logits[base + e0] = v;
    }
}

// ======================= conv2 aggregate + bias + LN stats =======================
__global__ __launch_bounds__(256) void k_agg2(
    const int* __restrict__ rowptr, const int* __restrict__ esrc, const int* __restrict__ eid,
    const float* __restrict__ logits, const float* __restrict__ xl, const float* __restrict__ bias,
    float* __restrict__ out, float* __restrict__ S)
{
    int w = threadIdx.x >> 6, lane = threadIdx.x & 63;
    int node = blockIdx.x * 4 + w;
    int beg = rowptr[node], end = rowptr[node + 1];
    float m = -1e30f;
    for (int j = beg + lane; j < end; j += 64) m = fmaxf(m, logits[eid[j]]);
    #pragma unroll
    for (int off = 32; off; off >>= 1) m = fmaxf(m, __shfl_xor(m, off));
    float acc = 0.f, dtot = 0.f;
    for (int b = beg; b < end; b += 64) {
        int j = b + lane;
        bool act = j < end;
        int e_ = act ? eid[j] : 0;
        int sR = act ? esrc[j] : 0;
        float ex = act ? expf(logits[e_] - m) : 0.f;
        float bs = ex;
        #pragma unroll
        for (int off = 32; off; off >>= 1) bs += __shfl_xor(bs, off);
        dtot += bs;
        int cnt = end - b; if (cnt > 64) cnt = 64;
        #pragma unroll 4
        for (int t = 0; t < cnt; t++) {
            float wgt = __shfl(ex, t);
            int s = __shfl(sR, t);
            if (lane < OUTD) acc += wgt * xl[(size_t)s * OUTD + lane];
        }
    }
    float s1 = 0.f, s2 = 0.f;
    if (lane < OUTD) {
        float o = ((end > beg) ? acc / (dtot + EPS_SM) : 0.f) + bias[lane];
        out[(size_t)node * OUTD + lane] = o;
        s1 = o; s2 = o * o;
    }
    #pragma unroll
    for (int off = 32; off; off >>= 1) { s1 += __shfl_xor(s1, off); s2 += __shfl_xor(s2, off); }
    __shared__ float ls1[4], ls2[4];
    if (lane == 0) { ls1[w] = s1; ls2[w] = s2; }
    __syncthreads();
    if (threadIdx.x == 0) {
        atomicAdd(S,     ls1[0] + ls1[1] + ls1[2] + ls1[3]);
        atomicAdd(S + 1, ls2[0] + ls2[1] + ls2[2] + ls2[3]);
    }
}

extern "C" void kernel_launch(void* const* d_in, const int* in_sizes, int n_in,
                              void* d_out, int out_size, void* d_ws, size_t ws_size,
                              hipStream_t stream)
{
    const int*   x    = (const int*)d_in[0];
    const int*   ei   = (const int*)d_in[1];
    const int*   srcA = ei;
    const int*   dstA = ei + N_EDGES;
    const float* ea   = (const float*)d_in[2];
    const float* emb  = (const float*)d_in[3];
    const float* Wl1  = (const float*)d_in[4];
    const float* bl1  = (const float*)d_in[5];
    const float* Wr1  = (const float*)d_in[6];
    const float* br1  = (const float*)d_in[7];
    const float* We1  = (const float*)d_in[8];
    const float* att1 = (const float*)d_in[9];
    const float* bias1= (const float*)d_in[10];
    const float* ln1w = (const float*)d_in[11];
    const float* ln1b = (const float*)d_in[12];
    const float* Wl2  = (const float*)d_in[13];
    const float* bl2  = (const float*)d_in[14];
    const float* Wr2  = (const float*)d_in[15];
    const float* br2  = (const float*)d_in[16];
    const float* We2  = (const float*)d_in[17];
    const float* att2 = (const float*)d_in[18];
    const float* bias2= (const float*)d_in[19];
    const float* ln2w = (const float*)d_in[20];
    const float* ln2b = (const float*)d_in[21];

    // workspace layout (float offsets); peak 28,760,004 floats = 115.1 MB
    float* W = (float*)d_ws;
    u16*   xl1b    = (u16*)W;                      // [0, 6.4M)
    u16*   xr1b    = (u16*)(W + 6400000);          // [6.4M, 12.8M)
    float* out1    = W + 12800000;                 // [12.8M, 25.6M)  (h1 in place)
    float* logits1 = W + 25600000;                 // [25.6M, 27.6M)  E*4
    int*   esrc    = (int*)(W + 27600000);         // E
    int*   eid     = (int*)(W + 28100000);         // E
    int*   rowptr  = (int*)(W + 28600000);         // N+1
    int*   cnt     = (int*)(W + 28660000);         // N
    int*   cursor  = (int*)(W + 28710000);         // N
    float* S       = W + 28760000;                 // 4
    // reuse (liveness-checked):
    float* xl2     = W;                            // [0, 2.5M)      after agg1
    float* xr2     = W + 2500000;                  // [2.5M, 5M)
    float* out2    = W + 6400000;                  // [6.4M, 8.9M)   xr1b dead after edge1
    float* logits2 = logits1;                      // after agg1
    float* h1      = out1;

    hipMemsetAsync(cnt, 0, N_NODES * sizeof(int), stream);
    hipMemsetAsync(cursor, 0, N_NODES * sizeof(int), stream);
    hipMemsetAsync(S, 0, 4 * sizeof(float), stream);

    // CSR build
    k_hist<<<(N_EDGES + 255) / 256, 256, 0, stream>>>(dstA, cnt);
    k_scan<<<1, 1024, 0, stream>>>(cnt, rowptr);
    k_scatter<<<(N_EDGES + 255) / 256, 256, 0, stream>>>(srcA, dstA, rowptr, cursor, eid, esrc);

    // conv1
    k_node1<<<1024, 256, 0, stream>>>(x, emb, Wl1, bl1, Wr1, br1, xl1b, xr1b);
    k_edge1<<<(N_EDGES + 63) / 64, 256, 0, stream>>>(srcA, dstA, ea, xl1b, xr1b, We1, att1, logits1);
    k_agg1<<<N_NODES, 256, 0, stream>>>(rowptr, esrc, eid, logits1, xl1b, bias1, out1, S);
    k_ln_apply_relu<<<(N_NODES * F1 + 255) / 256, 256, 0, stream>>>(out1, ln1w, ln1b, S, N_NODES * F1, F1);

    // conv2
    k_node2<<<1024, 256, 0, stream>>>(h1, Wl2, bl2, Wr2, br2, xl2, xr2);
    k_edge2<<<(N_EDGES + 63) / 64, 256, 0, stream>>>(srcA, dstA, ea, xl2, xr2, We2, att2, logits2);
    k_agg2<<<N_NODES / 4, 256, 0, stream>>>(rowptr, esrc, eid, logits2, xl2, bias2, out2, S + 2);
    k_ln_out<<<(N_NODES * OUTD + 255) / 256, 256, 0, stream>>>(out2, ln2w, ln2b, S + 2, N_NODES * OUTD, OUTD, (float*)d_out);
}

// Round 5
// 1016.219 us; speedup vs baseline: 2.4027x; 2.4027x over previous
//
#include <hip/hip_runtime.h>

#define N_NODES 50000
#define N_EDGES 500000
#define EMB 50
#define HID 64
#define OUTD 50
#define EDIM 28
#define HEADS 4
#define F1 256              // HEADS*HID
#define NEG 0.2f
#define EPS_SM 1e-16f
#define EPS_LN 1e-5f

typedef unsigned short u16;
typedef unsigned int u32;

__device__ __forceinline__ float b2f(u16 u) { return __uint_as_float(((u32)u) << 16); }
__device__ __forceinline__ u16 f2b(float f) {
    u32 u = __float_as_uint(f);
    u32 r = (u + 0x7FFFu + ((u >> 16) & 1u)) >> 16;
    return (u16)r;
}
__device__ __forceinline__ float lrelu(float x) { return x > 0.f ? x : NEG * x; }

// ======================= CSR build =======================
__global__ void k_hist(const int* __restrict__ dst, int* __restrict__ cnt) {
    int e = blockIdx.x * blockDim.x + threadIdx.x;
    if (e < N_EDGES) atomicAdd(&cnt[dst[e]], 1);
}

__global__ __launch_bounds__(1024) void k_scan(const int* __restrict__ cnt, int* __restrict__ rowptr) {
    __shared__ int part[1024];
    int tid = threadIdx.x;
    const int CH = (N_NODES + 1023) / 1024;   // 49
    int beg = tid * CH;
    int end = beg + CH; if (end > N_NODES) end = N_NODES;
    int s = 0;
    for (int i = beg; i < end && i >= beg; i++) s += cnt[i];
    part[tid] = s;
    __syncthreads();
    for (int off = 1; off < 1024; off <<= 1) {
        int v = (tid >= off) ? part[tid - off] : 0;
        __syncthreads();
        part[tid] += v;
        __syncthreads();
    }
    int run = (tid == 0) ? 0 : part[tid - 1];
    for (int i = beg; i < end && i >= beg; i++) { rowptr[i] = run; run += cnt[i]; }
    if (tid == 1023) rowptr[N_NODES] = run;
}

// also emits slotmap (edge -> CSR slot) so edge kernels can write logits in slot order
__global__ void k_scatter(const int* __restrict__ src, const int* __restrict__ dst,
                          const int* __restrict__ rowptr, int* __restrict__ cursor,
                          int* __restrict__ slotmap, int* __restrict__ esrc) {
    int e = blockIdx.x * blockDim.x + threadIdx.x;
    if (e >= N_EDGES) return;
    int d = dst[e];
    int pos = atomicAdd(&cursor[d], 1);
    int slot = rowptr[d] + pos;
    slotmap[e] = slot;
    esrc[slot] = src[e];
}

// ======================= partial-sum reducer (replaces same-address atomics) ===========
__global__ __launch_bounds__(256) void k_sumpart(const float* __restrict__ P, int n, float* __restrict__ S) {
    float s1 = 0.f, s2 = 0.f;
    int stride = gridDim.x * blockDim.x;
    for (int i = blockIdx.x * blockDim.x + threadIdx.x; i < n; i += stride) {
        s1 += P[2 * i]; s2 += P[2 * i + 1];
    }
    #pragma unroll
    for (int off = 32; off; off >>= 1) { s1 += __shfl_xor(s1, off); s2 += __shfl_xor(s2, off); }
    __shared__ float w1[4], w2[4];
    int w = threadIdx.x >> 6;
    if ((threadIdx.x & 63) == 0) { w1[w] = s1; w2[w] = s2; }
    __syncthreads();
    if (threadIdx.x == 0) {
        atomicAdd(S,     w1[0] + w1[1] + w1[2] + w1[3]);
        atomicAdd(S + 1, w2[0] + w2[1] + w2[2] + w2[3]);
    }
}

// ======================= conv1 node transform =======================
#define NT1 8
__global__ __launch_bounds__(256) void k_node1(
    const int* __restrict__ x, const float* __restrict__ emb,
    const float* __restrict__ Wl, const float* __restrict__ bl,
    const float* __restrict__ Wr, const float* __restrict__ br,
    u16* __restrict__ xl, u16* __restrict__ xr)
{
    __shared__ u16 wls[EMB * F1];
    __shared__ u16 wrs[EMB * F1];
    __shared__ float h0s[NT1 * EMB];
    __shared__ int xs[NT1];
    int tid = threadIdx.x;
    for (int i = tid; i < EMB * F1; i += 256) { wls[i] = f2b(Wl[i]); wrs[i] = f2b(Wr[i]); }
    float blr = bl[tid], brr = br[tid];
    __syncthreads();
    const int ntiles = N_NODES / NT1;   // 6250
    for (int tile = blockIdx.x; tile < ntiles; tile += gridDim.x) {
        int nb = tile * NT1;
        if (tid < NT1) xs[tid] = x[nb + tid];
        __syncthreads();
        for (int i = tid; i < NT1 * EMB; i += 256) {
            int nn = i / EMB, k = i - nn * EMB;
            h0s[i] = emb[(size_t)xs[nn] * EMB + k];
        }
        __syncthreads();
        float accl[NT1], accr[NT1];
        #pragma unroll
        for (int n = 0; n < NT1; n++) { accl[n] = blr; accr[n] = brr; }
        for (int k = 0; k < EMB; k++) {
            float wl_ = b2f(wls[k * F1 + tid]);
            float wr_ = b2f(wrs[k * F1 + tid]);
            #pragma unroll
            for (int n = 0; n < NT1; n++) {
                float h = h0s[n * EMB + k];
                accl[n] += h * wl_;
                accr[n] += h * wr_;
            }
        }
        #pragma unroll
        for (int n = 0; n < NT1; n++) {
            xl[(size_t)(nb + n) * F1 + tid] = f2b(accl[n]);
            xr[(size_t)(nb + n) * F1 + tid] = f2b(accr[n]);
        }
        __syncthreads();
    }
}

// ======================= conv1 edge logits (write in CSR slot order) ===================
__global__ __launch_bounds__(256) void k_edge1(
    const int* __restrict__ srcA, const int* __restrict__ dstA, const int* __restrict__ slotmap,
    const float* __restrict__ ea, const u16* __restrict__ xl, const u16* __restrict__ xr,
    const float* __restrict__ We, const float* __restrict__ att,
    float* __restrict__ logits)
{
    __shared__ float eas[64 * EDIM];
    __shared__ int ss[64], dd[64], sm[64];
    int tid = threadIdx.x;
    int w = tid >> 6, lane = tid & 63;
    float weR[EDIM];
    #pragma unroll
    for (int k = 0; k < EDIM; k++) weR[k] = We[k * F1 + tid];
    float attR = att[tid];
    int base = blockIdx.x * 64;
    int ne = N_EDGES - base; if (ne > 64) ne = 64;
    for (int i = tid; i < ne * EDIM; i += 256) eas[i] = ea[(size_t)base * EDIM + i];
    if (tid < ne) { ss[tid] = srcA[base + tid]; dd[tid] = dstA[base + tid]; sm[tid] = slotmap[base + tid]; }
    __syncthreads();
    #pragma unroll 2
    for (int e0 = 0; e0 < ne; e0++) {
        const float* er = eas + e0 * EDIM;
        float a0 = 0, a1 = 0, a2 = 0, a3 = 0;
        #pragma unroll
        for (int k = 0; k < EDIM; k += 4) {
            a0 += er[k]     * weR[k];
            a1 += er[k + 1] * weR[k + 1];
            a2 += er[k + 2] * weR[k + 2];
            a3 += er[k + 3] * weR[k + 3];
        }
        float xe = (a0 + a1) + (a2 + a3);
        int s = ss[e0], d = dd[e0];
        float v = lrelu(b2f(xl[(size_t)s * F1 + tid]) + b2f(xr[(size_t)d * F1 + tid]) + xe) * attR;
        #pragma unroll
        for (int off = 32; off; off >>= 1) v += __shfl_xor(v, off);
        if (lane == 0) logits[(size_t)sm[e0] * 4 + w] = v;
    }
}

// ======================= conv1 aggregate + bias + LN partials =======================
// one wave per (node, head); logits/esrc in slot order (coalesced); partial LN stats stored.
__global__ __launch_bounds__(256) void k_agg1(
    const int* __restrict__ rowptr, const int* __restrict__ esrc,
    const float* __restrict__ logits, const u16* __restrict__ xl, const float* __restrict__ bias,
    float* __restrict__ out, float* __restrict__ Spart)
{
    int node = blockIdx.x;
    int h = threadIdx.x >> 6, lane = threadIdx.x & 63;
    int beg = rowptr[node], end = rowptr[node + 1];
    int deg = end - beg;
    float acc = 0.f, dtot = 0.f;
    if (deg <= 64) {
        // fast path: one slot per lane, logits loaded once
        bool act = lane < deg;
        float lg = act ? logits[(size_t)(beg + lane) * 4 + h] : -1e30f;
        int sR = act ? esrc[beg + lane] : 0;
        float m = lg;
        #pragma unroll
        for (int off = 32; off; off >>= 1) m = fmaxf(m, __shfl_xor(m, off));
        float ex = act ? expf(lg - m) : 0.f;
        dtot = ex;
        #pragma unroll
        for (int off = 32; off; off >>= 1) dtot += __shfl_xor(dtot, off);
        #pragma unroll 4
        for (int t = 0; t < deg; t++) {
            float wgt = __shfl(ex, t);
            int s = __shfl(sR, t);
            acc += wgt * b2f(xl[(size_t)s * F1 + (h << 6) + lane]);
        }
    } else {
        float m = -1e30f;
        for (int j = beg + lane; j < end; j += 64) m = fmaxf(m, logits[(size_t)j * 4 + h]);
        #pragma unroll
        for (int off = 32; off; off >>= 1) m = fmaxf(m, __shfl_xor(m, off));
        for (int b = beg; b < end; b += 64) {
            int j = b + lane;
            bool act = j < end;
            float ex = act ? expf(logits[(size_t)j * 4 + h] - m) : 0.f;
            int sR = act ? esrc[j] : 0;
            float bs = ex;
            #pragma unroll
            for (int off = 32; off; off >>= 1) bs += __shfl_xor(bs, off);
            dtot += bs;
            int cnt = end - b; if (cnt > 64) cnt = 64;
            #pragma unroll 4
            for (int t = 0; t < cnt; t++) {
                float wgt = __shfl(ex, t);
                int s = __shfl(sR, t);
                acc += wgt * b2f(xl[(size_t)s * F1 + (h << 6) + lane]);
            }
        }
    }
    float o = ((deg > 0) ? acc / (dtot + EPS_SM) : 0.f) + bias[(h << 6) + lane];
    out[(size_t)node * F1 + (h << 6) + lane] = o;
    float s1 = o, s2 = o * o;
    #pragma unroll
    for (int off = 32; off; off >>= 1) { s1 += __shfl_xor(s1, off); s2 += __shfl_xor(s2, off); }
    __shared__ float ls1[4], ls2[4];
    if (lane == 0) { ls1[h] = s1; ls2[h] = s2; }
    __syncthreads();
    if (threadIdx.x == 0) {
        Spart[(size_t)node * 2]     = ls1[0] + ls1[1] + ls1[2] + ls1[3];
        Spart[(size_t)node * 2 + 1] = ls2[0] + ls2[1] + ls2[2] + ls2[3];
    }
}

// ======================= LayerNorm apply (+ReLU) =======================
__global__ void k_ln_apply_relu(
    float* v, const float* __restrict__ w, const float* __restrict__ b,
    const float* __restrict__ S, int M, int C)
{
    int i = blockIdx.x * blockDim.x + threadIdx.x;
    if (i >= M) return;
    float mu = S[0] / (float)M;
    float var = S[1] / (float)M - mu * mu;
    float inv = 1.f / (sqrtf(fmaxf(var, 0.f)) + EPS_LN);
    int c = i % C;
    float y = (v[i] - mu) * inv * w[c] + b[c];
    v[i] = fmaxf(y, 0.f);
}

__global__ void k_ln_out(
    const float* __restrict__ v, const float* __restrict__ w, const float* __restrict__ b,
    const float* __restrict__ S, int M, int C, float* __restrict__ out)
{
    int i = blockIdx.x * blockDim.x + threadIdx.x;
    if (i >= M) return;
    float mu = S[0] / (float)M;
    float var = S[1] / (float)M - mu * mu;
    float inv = 1.f / (sqrtf(fmaxf(var, 0.f)) + EPS_LN);
    int c = i % C;
    out[i] = (v[i] - mu) * inv * w[c] + b[c];
}

// ======================= conv2 node transform =======================
#define NT2 16
__global__ __launch_bounds__(256) void k_node2(
    const float* __restrict__ h, const float* __restrict__ Wl, const float* __restrict__ bl,
    const float* __restrict__ Wr, const float* __restrict__ br,
    float* __restrict__ xl, float* __restrict__ xr)
{
    __shared__ u16 wls[F1 * OUTD];
    __shared__ u16 wrs[F1 * OUTD];
    __shared__ float hs[NT2 * F1];
    int tid = threadIdx.x;
    int w = tid >> 6, lane = tid & 63;
    for (int i = tid; i < F1 * OUTD; i += 256) { wls[i] = f2b(Wl[i]); wrs[i] = f2b(Wr[i]); }
    float blr = (lane < OUTD) ? bl[lane] : 0.f;
    float brr = (lane < OUTD) ? br[lane] : 0.f;
    __syncthreads();
    const int ntiles = N_NODES / NT2;   // 3125
    for (int tile = blockIdx.x; tile < ntiles; tile += gridDim.x) {
        int nb = tile * NT2;
        for (int i = tid; i < NT2 * F1; i += 256) hs[i] = h[(size_t)nb * F1 + i];
        __syncthreads();
        if (lane < OUTD) {
            float accl[4] = {blr, blr, blr, blr};
            float accr[4] = {brr, brr, brr, brr};
            int nl = w * 4;
            for (int k = 0; k < F1; k++) {
                float wl_ = b2f(wls[k * OUTD + lane]);
                float wr_ = b2f(wrs[k * OUTD + lane]);
                #pragma unroll
                for (int n = 0; n < 4; n++) {
                    float hv = hs[(nl + n) * F1 + k];
                    accl[n] += hv * wl_;
                    accr[n] += hv * wr_;
                }
            }
            #pragma unroll
            for (int n = 0; n < 4; n++) {
                xl[(size_t)(nb + nl + n) * OUTD + lane] = accl[n];
                xr[(size_t)(nb + nl + n) * OUTD + lane] = accr[n];
            }
        }
        __syncthreads();
    }
}

// ======================= conv2 edge logits (slot order) =======================
__global__ __launch_bounds__(256) void k_edge2(
    const int* __restrict__ srcA, const int* __restrict__ dstA, const int* __restrict__ slotmap,
    const float* __restrict__ ea, const float* __restrict__ xl, const float* __restrict__ xr,
    const float* __restrict__ We, const float* __restrict__ att,
    float* __restrict__ logits)
{
    __shared__ float eas[64 * EDIM];
    __shared__ int ss[64], dd[64], sm[64];
    int tid = threadIdx.x;
    int w = tid >> 6, lane = tid & 63;
    float weR[EDIM];
    float attR = 0.f;
    if (lane < OUTD) {
        #pragma unroll
        for (int k = 0; k < EDIM; k++) weR[k] = We[k * OUTD + lane];
        attR = att[lane];
    } else {
        #pragma unroll
        for (int k = 0; k < EDIM; k++) weR[k] = 0.f;
    }
    int base = blockIdx.x * 64;
    int ne = N_EDGES - base; if (ne > 64) ne = 64;
    for (int i = tid; i < ne * EDIM; i += 256) eas[i] = ea[(size_t)base * EDIM + i];
    if (tid < ne) { ss[tid] = srcA[base + tid]; dd[tid] = dstA[base + tid]; sm[tid] = slotmap[base + tid]; }
    __syncthreads();
    for (int t = 0; t < 16; t++) {
        int e0 = (w << 4) + t;
        if (e0 >= ne) break;
        const float* er = eas + e0 * EDIM;
        float a0 = 0, a1 = 0, a2 = 0, a3 = 0;
        #pragma unroll
        for (int k = 0; k < EDIM; k += 4) {
            a0 += er[k]     * weR[k];
            a1 += er[k + 1] * weR[k + 1];
            a2 += er[k + 2] * weR[k + 2];
            a3 += er[k + 3] * weR[k + 3];
        }
        float xe = (a0 + a1) + (a2 + a3);
        int s = ss[e0], d = dd[e0];
        float v = 0.f;
        if (lane < OUTD)
            v = lrelu(xl[(size_t)s * OUTD + lane] + xr[(size_t)d * OUTD + lane] + xe) * attR;
        #pragma unroll
        for (int off = 32; off; off >>= 1) v += __shfl_xor(v, off);
        if (lane == 0) logits[sm[e0]] = v;
    }
}

// ======================= conv2 aggregate + bias + LN partials =======================
__global__ __launch_bounds__(256) void k_agg2(
    const int* __restrict__ rowptr, const int* __restrict__ esrc,
    const float* __restrict__ logits, const float* __restrict__ xl, const float* __restrict__ bias,
    float* __restrict__ out, float* __restrict__ Spart)
{
    int w = threadIdx.x >> 6, lane = threadIdx.x & 63;
    int node = blockIdx.x * 4 + w;
    int beg = rowptr[node], end = rowptr[node + 1];
    int deg = end - beg;
    float acc = 0.f, dtot = 0.f;
    if (deg <= 64) {
        bool act = lane < deg;
        float lg = act ? logits[beg + lane] : -1e30f;
        int sR = act ? esrc[beg + lane] : 0;
        float m = lg;
        #pragma unroll
        for (int off = 32; off; off >>= 1) m = fmaxf(m, __shfl_xor(m, off));
        float ex = act ? expf(lg - m) : 0.f;
        dtot = ex;
        #pragma unroll
        for (int off = 32; off; off >>= 1) dtot += __shfl_xor(dtot, off);
        #pragma unroll 4
        for (int t = 0; t < deg; t++) {
            float wgt = __shfl(ex, t);
            int s = __shfl(sR, t);
            if (lane < OUTD) acc += wgt * xl[(size_t)s * OUTD + lane];
        }
    } else {
        float m = -1e30f;
        for (int j = beg + lane; j < end; j += 64) m = fmaxf(m, logits[j]);
        #pragma unroll
        for (int off = 32; off; off >>= 1) m = fmaxf(m, __shfl_xor(m, off));
        for (int b = beg; b < end; b += 64) {
            int j = b + lane;
            bool act = j < end;
            float ex = act ? expf(logits[j] - m) : 0.f;
            int sR = act ? esrc[j] : 0;
            float bs = ex;
            #pragma unroll
            for (int off = 32; off; off >>= 1) bs += __shfl_xor(bs, off);
            dtot += bs;
            int cnt = end - b; if (cnt > 64) cnt = 64;
            #pragma unroll 4
            for (int t = 0; t < cnt; t++) {
                float wgt = __shfl(ex, t);
                int s = __shfl(sR, t);
                if (lane < OUTD) acc += wgt * xl[(size_t)s * OUTD + lane];
            }
        }
    }
    float s1 = 0.f, s2 = 0.f;
    if (lane < OUTD) {
        float o = ((deg > 0) ? acc / (dtot + EPS_SM) : 0.f) + bias[lane];
        out[(size_t)node * OUTD + lane] = o;
        s1 = o; s2 = o * o;
    }
    #pragma unroll
    for (int off = 32; off; off >>= 1) { s1 += __shfl_xor(s1, off); s2 += __shfl_xor(s2, off); }
    __shared__ float ls1[4], ls2[4];
    if (lane == 0) { ls1[w] = s1; ls2[w] = s2; }
    __syncthreads();
    if (threadIdx.x == 0) {
        Spart[(size_t)blockIdx.x * 2]     = ls1[0] + ls1[1] + ls1[2] + ls1[3];
        Spart[(size_t)blockIdx.x * 2 + 1] = ls2[0] + ls2[1] + ls2[2] + ls2[3];
    }
}

extern "C" void kernel_launch(void* const* d_in, const int* in_sizes, int n_in,
                              void* d_out, int out_size, void* d_ws, size_t ws_size,
                              hipStream_t stream)
{
    const int*   x    = (const int*)d_in[0];
    const int*   ei   = (const int*)d_in[1];
    const int*   srcA = ei;
    const int*   dstA = ei + N_EDGES;
    const float* ea   = (const float*)d_in[2];
    const float* emb  = (const float*)d_in[3];
    const float* Wl1  = (const float*)d_in[4];
    const float* bl1  = (const float*)d_in[5];
    const float* Wr1  = (const float*)d_in[6];
    const float* br1  = (const float*)d_in[7];
    const float* We1  = (const float*)d_in[8];
    const float* att1 = (const float*)d_in[9];
    const float* bias1= (const float*)d_in[10];
    const float* ln1w = (const float*)d_in[11];
    const float* ln1b = (const float*)d_in[12];
    const float* Wl2  = (const float*)d_in[13];
    const float* bl2  = (const float*)d_in[14];
    const float* Wr2  = (const float*)d_in[15];
    const float* br2  = (const float*)d_in[16];
    const float* We2  = (const float*)d_in[17];
    const float* att2 = (const float*)d_in[18];
    const float* bias2= (const float*)d_in[19];
    const float* ln2w = (const float*)d_in[20];
    const float* ln2b = (const float*)d_in[21];

    // workspace layout (float offsets); peak ~28.97M floats = 115.9 MB
    float* W = (float*)d_ws;
    u16*   xl1b    = (u16*)W;                      // [0, 6.4M)
    u16*   xr1b    = (u16*)(W + 6400000);          // [6.4M, 12.8M)
    float* out1    = W + 12800000;                 // [12.8M, 25.6M)  (h1 in place)
    float* logits1 = W + 25600000;                 // [25.6M, 27.6M)  E*4
    int*   esrc    = (int*)(W + 27600000);         // E
    int*   slotmap = (int*)(W + 28100000);         // E
    int*   rowptr  = (int*)(W + 28600000);         // N+1
    int*   cnt     = (int*)(W + 28660000);         // N
    int*   cursor  = (int*)(W + 28710000);         // N
    float* Spart   = W + 28760000;                 // 2*N = 100k  [28.76M, 28.86M)
    float* S       = W + 28960000;                 // 4
    // reuse (liveness-checked):
    float* xl2     = W;                            // [0, 2.5M)      after agg1
    float* xr2     = W + 2500000;                  // [2.5M, 5M)
    float* out2    = W + 6400000;                  // [6.4M, 8.9M)   xr1b dead after edge1
    float* logits2 = logits1;                      // after agg1
    float* h1      = out1;

    hipMemsetAsync(cnt, 0, N_NODES * sizeof(int), stream);
    hipMemsetAsync(cursor, 0, N_NODES * sizeof(int), stream);
    hipMemsetAsync(S, 0, 4 * sizeof(float), stream);

    // CSR build
    k_hist<<<(N_EDGES + 255) / 256, 256, 0, stream>>>(dstA, cnt);
    k_scan<<<1, 1024, 0, stream>>>(cnt, rowptr);
    k_scatter<<<(N_EDGES + 255) / 256, 256, 0, stream>>>(srcA, dstA, rowptr, cursor, slotmap, esrc);

    // conv1
    k_node1<<<1024, 256, 0, stream>>>(x, emb, Wl1, bl1, Wr1, br1, xl1b, xr1b);
    k_edge1<<<(N_EDGES + 63) / 64, 256, 0, stream>>>(srcA, dstA, slotmap, ea, xl1b, xr1b, We1, att1, logits1);
    k_agg1<<<N_NODES, 256, 0, stream>>>(rowptr, esrc, logits1, xl1b, bias1, out1, Spart);
    k_sumpart<<<32, 256, 0, stream>>>(Spart, N_NODES, S);
    k_ln_apply_relu<<<(N_NODES * F1 + 255) / 256, 256, 0, stream>>>(out1, ln1w, ln1b, S, N_NODES * F1, F1);

    // conv2
    k_node2<<<1024, 256, 0, stream>>>(h1, Wl2, bl2, Wr2, br2, xl2, xr2);
    k_edge2<<<(N_EDGES + 63) / 64, 256, 0, stream>>>(srcA, dstA, slotmap, ea, xl2, xr2, We2, att2, logits2);
    k_agg2<<<N_NODES / 4, 256, 0, stream>>>(rowptr, esrc, logits2, xl2, bias2, out2, Spart);
    k_sumpart<<<32, 256, 0, stream>>>(Spart, N_NODES / 4, S + 2);
    k_ln_out<<<(N_NODES * OUTD + 255) / 256, 256, 0, stream>>>(out2, ln2w, ln2b, S + 2, N_NODES * OUTD, OUTD, (float*)d_out);
}

// Round 6
// 974.548 us; speedup vs baseline: 2.5055x; 1.0428x over previous
//
#include <hip/hip_runtime.h>

#define N_NODES 50000
#define N_EDGES 500000
#define EMB 50
#define HID 64
#define OUTD 50
#define EDIM 28
#define HEADS 4
#define F1 256              // HEADS*HID
#define NEG 0.2f
#define EPS_SM 1e-16f
#define EPS_LN 1e-5f

typedef unsigned short u16;
typedef unsigned int u32;

__device__ __forceinline__ float b2f(u16 u) { return __uint_as_float(((u32)u) << 16); }
__device__ __forceinline__ u16 f2b(float f) {
    u32 u = __float_as_uint(f);
    u32 r = (u + 0x7FFFu + ((u >> 16) & 1u)) >> 16;
    return (u16)r;
}
__device__ __forceinline__ float lrelu(float x) { return x > 0.f ? x : NEG * x; }

// ======================= CSR build =======================
__global__ void k_hist(const int* __restrict__ dst, int* __restrict__ cnt) {
    int e = blockIdx.x * blockDim.x + threadIdx.x;
    if (e < N_EDGES) atomicAdd(&cnt[dst[e]], 1);
}

__global__ __launch_bounds__(1024) void k_scan(const int* __restrict__ cnt, int* __restrict__ rowptr) {
    __shared__ int part[1024];
    int tid = threadIdx.x;
    const int CH = (N_NODES + 1023) / 1024;   // 49
    int beg = tid * CH;
    int end = beg + CH; if (end > N_NODES) end = N_NODES;
    int s = 0;
    for (int i = beg; i < end && i >= beg; i++) s += cnt[i];
    part[tid] = s;
    __syncthreads();
    for (int off = 1; off < 1024; off <<= 1) {
        int v = (tid >= off) ? part[tid - off] : 0;
        __syncthreads();
        part[tid] += v;
        __syncthreads();
    }
    int run = (tid == 0) ? 0 : part[tid - 1];
    for (int i = beg; i < end && i >= beg; i++) { rowptr[i] = run; run += cnt[i]; }
    if (tid == 1023) rowptr[N_NODES] = run;
}

// packs (edge id, src) per CSR slot so the fused kernels do one scalar dwordx2 per edge
__global__ void k_scatter(const int* __restrict__ src, const int* __restrict__ dst,
                          const int* __restrict__ rowptr, int* __restrict__ cursor,
                          int2* __restrict__ epk) {
    int e = blockIdx.x * blockDim.x + threadIdx.x;
    if (e >= N_EDGES) return;
    int d = dst[e];
    int pos = atomicAdd(&cursor[d], 1);
    epk[rowptr[d] + pos] = make_int2(e, src[e]);
}

// ======================= partial-sum reducer =======================
__global__ __launch_bounds__(256) void k_sumpart(const float* __restrict__ P, int n, float* __restrict__ S) {
    float s1 = 0.f, s2 = 0.f;
    int stride = gridDim.x * blockDim.x;
    for (int i = blockIdx.x * blockDim.x + threadIdx.x; i < n; i += stride) {
        s1 += P[2 * i]; s2 += P[2 * i + 1];
    }
    #pragma unroll
    for (int off = 32; off; off >>= 1) { s1 += __shfl_xor(s1, off); s2 += __shfl_xor(s2, off); }
    __shared__ float w1[4], w2[4];
    int w = threadIdx.x >> 6;
    if ((threadIdx.x & 63) == 0) { w1[w] = s1; w2[w] = s2; }
    __syncthreads();
    if (threadIdx.x == 0) {
        atomicAdd(S,     w1[0] + w1[1] + w1[2] + w1[3]);
        atomicAdd(S + 1, w2[0] + w2[1] + w2[2] + w2[3]);
    }
}

// ======================= conv1 node transform =======================
#define NT1 8
__global__ __launch_bounds__(256) void k_node1(
    const int* __restrict__ x, const float* __restrict__ emb,
    const float* __restrict__ Wl, const float* __restrict__ bl,
    const float* __restrict__ Wr, const float* __restrict__ br,
    u16* __restrict__ xl, u16* __restrict__ xr)
{
    __shared__ u16 wls[EMB * F1];
    __shared__ u16 wrs[EMB * F1];
    __shared__ float h0s[NT1 * EMB];
    __shared__ int xs[NT1];
    int tid = threadIdx.x;
    for (int i = tid; i < EMB * F1; i += 256) { wls[i] = f2b(Wl[i]); wrs[i] = f2b(Wr[i]); }
    float blr = bl[tid], brr = br[tid];
    __syncthreads();
    const int ntiles = N_NODES / NT1;   // 6250
    for (int tile = blockIdx.x; tile < ntiles; tile += gridDim.x) {
        int nb = tile * NT1;
        if (tid < NT1) xs[tid] = x[nb + tid];
        __syncthreads();
        for (int i = tid; i < NT1 * EMB; i += 256) {
            int nn = i / EMB, k = i - nn * EMB;
            h0s[i] = emb[(size_t)xs[nn] * EMB + k];
        }
        __syncthreads();
        float accl[NT1], accr[NT1];
        #pragma unroll
        for (int n = 0; n < NT1; n++) { accl[n] = blr; accr[n] = brr; }
        for (int k = 0; k < EMB; k++) {
            float wl_ = b2f(wls[k * F1 + tid]);
            float wr_ = b2f(wrs[k * F1 + tid]);
            #pragma unroll
            for (int n = 0; n < NT1; n++) {
                float h = h0s[n * EMB + k];
                accl[n] += h * wl_;
                accr[n] += h * wr_;
            }
        }
        #pragma unroll
        for (int n = 0; n < NT1; n++) {
            xl[(size_t)(nb + n) * F1 + tid] = f2b(accl[n]);
            xr[(size_t)(nb + n) * F1 + tid] = f2b(accr[n]);
        }
        __syncthreads();
    }
}

// ======================= conv1 fused edge-logit + online softmax + aggregate ===========
// block = node; 4 waves = 4 heads; lane = column within head; ea/epk via wave-uniform loads
__global__ __launch_bounds__(256) void k_fused1(
    const int* __restrict__ rowptr, const int2* __restrict__ epk,
    const float* __restrict__ ea, const u16* __restrict__ xl, const u16* __restrict__ xr,
    const float* __restrict__ We, const float* __restrict__ att, const float* __restrict__ bias,
    float* __restrict__ out, float* __restrict__ Spart)
{
    int node = blockIdx.x;
    int tid = threadIdx.x;          // global column 0..255
    int h = tid >> 6, lane = tid & 63;
    float weR[EDIM];
    #pragma unroll
    for (int k = 0; k < EDIM; k++) weR[k] = We[k * F1 + tid];
    float attR = att[tid];
    float xr_d = b2f(xr[(size_t)node * F1 + tid]);
    int beg = rowptr[node], end = rowptr[node + 1];
    float m = -1e30f, acc = 0.f, dtot = 0.f;
    for (int j = beg; j < end; j++) {
        int2 p = epk[j];            // wave-uniform -> scalar load
        int e = p.x, s = p.y;
        const float* er = ea + (size_t)e * EDIM;   // wave-uniform rows -> s_load
        float xl_s = b2f(xl[(size_t)s * F1 + tid]);
        float a0 = 0, a1 = 0, a2 = 0, a3 = 0;
        #pragma unroll
        for (int k = 0; k < EDIM; k += 4) {
            a0 += er[k]     * weR[k];
            a1 += er[k + 1] * weR[k + 1];
            a2 += er[k + 2] * weR[k + 2];
            a3 += er[k + 3] * weR[k + 3];
        }
        float v = lrelu(xl_s + xr_d + (a0 + a1) + (a2 + a3)) * attR;
        #pragma unroll
        for (int off = 32; off; off >>= 1) v += __shfl_xor(v, off);   // logit, in all lanes
        float mn = fmaxf(m, v);
        float scale = __expf(m - mn);       // 0 on first iteration (m=-1e30)
        float p_ = __expf(v - mn);
        acc  = acc  * scale + p_ * xl_s;
        dtot = dtot * scale + p_;
        m = mn;
    }
    float o = ((end > beg) ? acc / (dtot + EPS_SM) : 0.f) + bias[tid];
    out[(size_t)node * F1 + tid] = o;
    float s1 = o, s2 = o * o;
    #pragma unroll
    for (int off = 32; off; off >>= 1) { s1 += __shfl_xor(s1, off); s2 += __shfl_xor(s2, off); }
    __shared__ float ls1[4], ls2[4];
    if (lane == 0) { ls1[h] = s1; ls2[h] = s2; }
    __syncthreads();
    if (tid == 0) {
        Spart[(size_t)node * 2]     = ls1[0] + ls1[1] + ls1[2] + ls1[3];
        Spart[(size_t)node * 2 + 1] = ls2[0] + ls2[1] + ls2[2] + ls2[3];
    }
}

// ======================= LayerNorm apply (+ReLU) =======================
__global__ void k_ln_apply_relu(
    float* v, const float* __restrict__ w, const float* __restrict__ b,
    const float* __restrict__ S, int M, int C)
{
    int i = blockIdx.x * blockDim.x + threadIdx.x;
    if (i >= M) return;
    float mu = S[0] / (float)M;
    float var = S[1] / (float)M - mu * mu;
    float inv = 1.f / (sqrtf(fmaxf(var, 0.f)) + EPS_LN);
    int c = i % C;
    float y = (v[i] - mu) * inv * w[c] + b[c];
    v[i] = fmaxf(y, 0.f);
}

__global__ void k_ln_out(
    const float* __restrict__ v, const float* __restrict__ w, const float* __restrict__ b,
    const float* __restrict__ S, int M, int C, float* __restrict__ out)
{
    int i = blockIdx.x * blockDim.x + threadIdx.x;
    if (i >= M) return;
    float mu = S[0] / (float)M;
    float var = S[1] / (float)M - mu * mu;
    float inv = 1.f / (sqrtf(fmaxf(var, 0.f)) + EPS_LN);
    int c = i % C;
    out[i] = (v[i] - mu) * inv * w[c] + b[c];
}

// ======================= conv2 node transform =======================
#define NT2 16
__global__ __launch_bounds__(256) void k_node2(
    const float* __restrict__ h, const float* __restrict__ Wl, const float* __restrict__ bl,
    const float* __restrict__ Wr, const float* __restrict__ br,
    float* __restrict__ xl, float* __restrict__ xr)
{
    __shared__ u16 wls[F1 * OUTD];
    __shared__ u16 wrs[F1 * OUTD];
    __shared__ float hs[NT2 * F1];
    int tid = threadIdx.x;
    int w = tid >> 6, lane = tid & 63;
    for (int i = tid; i < F1 * OUTD; i += 256) { wls[i] = f2b(Wl[i]); wrs[i] = f2b(Wr[i]); }
    float blr = (lane < OUTD) ? bl[lane] : 0.f;
    float brr = (lane < OUTD) ? br[lane] : 0.f;
    __syncthreads();
    const int ntiles = N_NODES / NT2;   // 3125
    for (int tile = blockIdx.x; tile < ntiles; tile += gridDim.x) {
        int nb = tile * NT2;
        for (int i = tid; i < NT2 * F1; i += 256) hs[i] = h[(size_t)nb * F1 + i];
        __syncthreads();
        if (lane < OUTD) {
            float accl[4] = {blr, blr, blr, blr};
            float accr[4] = {brr, brr, brr, brr};
            int nl = w * 4;
            for (int k = 0; k < F1; k++) {
                float wl_ = b2f(wls[k * OUTD + lane]);
                float wr_ = b2f(wrs[k * OUTD + lane]);
                #pragma unroll
                for (int n = 0; n < 4; n++) {
                    float hv = hs[(nl + n) * F1 + k];
                    accl[n] += hv * wl_;
                    accr[n] += hv * wr_;
                }
            }
            #pragma unroll
            for (int n = 0; n < 4; n++) {
                xl[(size_t)(nb + nl + n) * OUTD + lane] = accl[n];
                xr[(size_t)(nb + nl + n) * OUTD + lane] = accr[n];
            }
        }
        __syncthreads();
    }
}

// ======================= conv2 fused (heads=1, C=50); wave = node =======================
__global__ __launch_bounds__(256) void k_fused2(
    const int* __restrict__ rowptr, const int2* __restrict__ epk,
    const float* __restrict__ ea, const float* __restrict__ xl, const float* __restrict__ xr,
    const float* __restrict__ We, const float* __restrict__ att, const float* __restrict__ bias,
    float* __restrict__ out, float* __restrict__ Spart)
{
    int w = threadIdx.x >> 6, lane = threadIdx.x & 63;
    int node = blockIdx.x * 4 + w;
    bool col = lane < OUTD;
    float weR[EDIM];
    #pragma unroll
    for (int k = 0; k < EDIM; k++) weR[k] = col ? We[k * OUTD + lane] : 0.f;
    float attR = col ? att[lane] : 0.f;
    float xr_d = col ? xr[(size_t)node * OUTD + lane] : 0.f;
    int beg = rowptr[node], end = rowptr[node + 1];
    float m = -1e30f, acc = 0.f, dtot = 0.f;
    for (int j = beg; j < end; j++) {
        int2 p = epk[j];
        int e = p.x, s = p.y;
        const float* er = ea + (size_t)e * EDIM;
        float xl_s = col ? xl[(size_t)s * OUTD + lane] : 0.f;
        float a0 = 0, a1 = 0, a2 = 0, a3 = 0;
        #pragma unroll
        for (int k = 0; k < EDIM; k += 4) {
            a0 += er[k]     * weR[k];
            a1 += er[k + 1] * weR[k + 1];
            a2 += er[k + 2] * weR[k + 2];
            a3 += er[k + 3] * weR[k + 3];
        }
        float v = col ? lrelu(xl_s + xr_d + (a0 + a1) + (a2 + a3)) * attR : 0.f;
        #pragma unroll
        for (int off = 32; off; off >>= 1) v += __shfl_xor(v, off);
        float mn = fmaxf(m, v);
        float scale = __expf(m - mn);
        float p_ = __expf(v - mn);
        acc  = acc  * scale + p_ * xl_s;
        dtot = dtot * scale + p_;
        m = mn;
    }
    float s1 = 0.f, s2 = 0.f;
    if (col) {
        float o = ((end > beg) ? acc / (dtot + EPS_SM) : 0.f) + bias[lane];
        out[(size_t)node * OUTD + lane] = o;
        s1 = o; s2 = o * o;
    }
    #pragma unroll
    for (int off = 32; off; off >>= 1) { s1 += __shfl_xor(s1, off); s2 += __shfl_xor(s2, off); }
    __shared__ float ls1[4], ls2[4];
    if (lane == 0) { ls1[w] = s1; ls2[w] = s2; }
    __syncthreads();
    if (threadIdx.x == 0) {
        Spart[(size_t)blockIdx.x * 2]     = ls1[0] + ls1[1] + ls1[2] + ls1[3];
        Spart[(size_t)blockIdx.x * 2 + 1] = ls2[0] + ls2[1] + ls2[2] + ls2[3];
    }
}

extern "C" void kernel_launch(void* const* d_in, const int* in_sizes, int n_in,
                              void* d_out, int out_size, void* d_ws, size_t ws_size,
                              hipStream_t stream)
{
    const int*   x    = (const int*)d_in[0];
    const int*   ei   = (const int*)d_in[1];
    const int*   srcA = ei;
    const int*   dstA = ei + N_EDGES;
    const float* ea   = (const float*)d_in[2];
    const float* emb  = (const float*)d_in[3];
    const float* Wl1  = (const float*)d_in[4];
    const float* bl1  = (const float*)d_in[5];
    const float* Wr1  = (const float*)d_in[6];
    const float* br1  = (const float*)d_in[7];
    const float* We1  = (const float*)d_in[8];
    const float* att1 = (const float*)d_in[9];
    const float* bias1= (const float*)d_in[10];
    const float* ln1w = (const float*)d_in[11];
    const float* ln1b = (const float*)d_in[12];
    const float* Wl2  = (const float*)d_in[13];
    const float* bl2  = (const float*)d_in[14];
    const float* Wr2  = (const float*)d_in[15];
    const float* br2  = (const float*)d_in[16];
    const float* We2  = (const float*)d_in[17];
    const float* att2 = (const float*)d_in[18];
    const float* bias2= (const float*)d_in[19];
    const float* ln2w = (const float*)d_in[20];
    const float* ln2b = (const float*)d_in[21];

    // workspace layout (float offsets); peak ~26.87M floats = 107.5 MB
    float* W = (float*)d_ws;
    u16*   xl1b    = (u16*)W;                      // [0, 6.4M)
    u16*   xr1b    = (u16*)(W + 6400000);          // [6.4M, 12.8M)
    float* out1    = W + 12800000;                 // [12.8M, 25.6M)  (h1 in place)
    int2*  epk     = (int2*)(W + 25600000);        // E int2 = 1M ints [25.6M, 26.6M)
    int*   rowptr  = (int*)(W + 26600000);         // N+1
    int*   cnt     = (int*)(W + 26660000);         // N
    int*   cursor  = (int*)(W + 26710000);         // N
    float* Spart   = W + 26760000;                 // 2*N [26.76M, 26.86M)
    float* S       = W + 26870000;                 // 4
    // reuse (liveness-checked):
    float* xl2     = W;                            // [0, 2.5M)    xl1b dead after fused1
    float* xr2     = W + 2500000;                  // [2.5M, 5M)
    float* out2    = W + 6400000;                  // [6.4M, 8.9M) xr1b dead after fused1
    float* h1      = out1;

    hipMemsetAsync(cnt, 0, N_NODES * sizeof(int), stream);
    hipMemsetAsync(cursor, 0, N_NODES * sizeof(int), stream);
    hipMemsetAsync(S, 0, 4 * sizeof(float), stream);

    // CSR build
    k_hist<<<(N_EDGES + 255) / 256, 256, 0, stream>>>(dstA, cnt);
    k_scan<<<1, 1024, 0, stream>>>(cnt, rowptr);
    k_scatter<<<(N_EDGES + 255) / 256, 256, 0, stream>>>(srcA, dstA, rowptr, cursor, epk);

    // conv1
    k_node1<<<1024, 256, 0, stream>>>(x, emb, Wl1, bl1, Wr1, br1, xl1b, xr1b);
    k_fused1<<<N_NODES, 256, 0, stream>>>(rowptr, epk, ea, xl1b, xr1b, We1, att1, bias1, out1, Spart);
    k_sumpart<<<32, 256, 0, stream>>>(Spart, N_NODES, S);
    k_ln_apply_relu<<<(N_NODES * F1 + 255) / 256, 256, 0, stream>>>(out1, ln1w, ln1b, S, N_NODES * F1, F1);

    // conv2
    k_node2<<<1024, 256, 0, stream>>>(h1, Wl2, bl2, Wr2, br2, xl2, xr2);
    k_fused2<<<N_NODES / 4, 256, 0, stream>>>(rowptr, epk, ea, xl2, xr2, We2, att2, bias2, out2, Spart);
    k_sumpart<<<32, 256, 0, stream>>>(Spart, N_NODES / 4, S + 2);
    k_ln_out<<<(N_NODES * OUTD + 255) / 256, 256, 0, stream>>>(out2, ln2w, ln2b, S + 2, N_NODES * OUTD, OUTD, (float*)d_out);
}

// Round 7
// 910.974 us; speedup vs baseline: 2.6803x; 1.0698x over previous
//
#include <hip/hip_runtime.h>

#define N_NODES 50000
#define N_EDGES 500000
#define EMB 50
#define HID 64
#define OUTD 50
#define EDIM 28
#define HEADS 4
#define F1 256              // HEADS*HID
#define NEG 0.2f
#define EPS_SM 1e-16f
#define EPS_LN 1e-5f

typedef unsigned short u16;
typedef unsigned int u32;
typedef _Float16 h2 __attribute__((ext_vector_type(2)));

#if defined(__has_builtin)
#if __has_builtin(__builtin_amdgcn_fdot2)
#define HAS_FDOT2 1
#endif
#endif
#ifndef HAS_FDOT2
#define HAS_FDOT2 0
#endif

__device__ __forceinline__ float b2f(u16 u) { return __uint_as_float(((u32)u) << 16); }
__device__ __forceinline__ u16 f2b(float f) {
    u32 u = __float_as_uint(f);
    u32 r = (u + 0x7FFFu + ((u >> 16) & 1u)) >> 16;
    return (u16)r;
}
__device__ __forceinline__ float lrelu(float x) { return x > 0.f ? x : NEG * x; }

// ======================= CSR build =======================
__global__ void k_hist(const int* __restrict__ dst, int* __restrict__ cnt) {
    int e = blockIdx.x * blockDim.x + threadIdx.x;
    if (e < N_EDGES) atomicAdd(&cnt[dst[e]], 1);
}

__global__ __launch_bounds__(1024) void k_scan(const int* __restrict__ cnt, int* __restrict__ rowptr) {
    __shared__ int part[1024];
    int tid = threadIdx.x;
    const int CH = (N_NODES + 1023) / 1024;   // 49
    int beg = tid * CH;
    int end = beg + CH; if (end > N_NODES) end = N_NODES;
    int s = 0;
    for (int i = beg; i < end && i >= beg; i++) s += cnt[i];
    part[tid] = s;
    __syncthreads();
    for (int off = 1; off < 1024; off <<= 1) {
        int v = (tid >= off) ? part[tid - off] : 0;
        __syncthreads();
        part[tid] += v;
        __syncthreads();
    }
    int run = (tid == 0) ? 0 : part[tid - 1];
    for (int i = beg; i < end && i >= beg; i++) { rowptr[i] = run; run += cnt[i]; }
    if (tid == 1023) rowptr[N_NODES] = run;
}

__global__ void k_scatter(const int* __restrict__ src, const int* __restrict__ dst,
                          const int* __restrict__ rowptr, int* __restrict__ cursor,
                          int2* __restrict__ epk) {
    int e = blockIdx.x * blockDim.x + threadIdx.x;
    if (e >= N_EDGES) return;
    int d = dst[e];
    int pos = atomicAdd(&cursor[d], 1);
    epk[rowptr[d] + pos] = make_int2(e, src[e]);
}

// ======================= ea -> f16 (padded rows of 32 halves) =======================
__global__ void k_tohalf(const float* __restrict__ a, _Float16* __restrict__ o) {
    int i = blockIdx.x * blockDim.x + threadIdx.x;
    if (i >= N_EDGES * 7) return;
    int e = i / 7, part = i - e * 7;
    float4 v = *(const float4*)(a + (size_t)e * EDIM + part * 4);
    h2 p0 = {(_Float16)v.x, (_Float16)v.y};
    h2 p1 = {(_Float16)v.z, (_Float16)v.w};
    *(uint2*)(o + (size_t)e * 32 + part * 4) =
        make_uint2(__builtin_bit_cast(unsigned, p0), __builtin_bit_cast(unsigned, p1));
}

// ======================= partial-sum reducer =======================
__global__ __launch_bounds__(256) void k_sumpart(const float* __restrict__ P, int n, float* __restrict__ S) {
    float s1 = 0.f, s2 = 0.f;
    int stride = gridDim.x * blockDim.x;
    for (int i = blockIdx.x * blockDim.x + threadIdx.x; i < n; i += stride) {
        s1 += P[2 * i]; s2 += P[2 * i + 1];
    }
    #pragma unroll
    for (int off = 32; off; off >>= 1) { s1 += __shfl_xor(s1, off); s2 += __shfl_xor(s2, off); }
    __shared__ float w1[4], w2[4];
    int w = threadIdx.x >> 6;
    if ((threadIdx.x & 63) == 0) { w1[w] = s1; w2[w] = s2; }
    __syncthreads();
    if (threadIdx.x == 0) {
        atomicAdd(S,     w1[0] + w1[1] + w1[2] + w1[3]);
        atomicAdd(S + 1, w2[0] + w2[1] + w2[2] + w2[3]);
    }
}

// ======================= conv1 node transform =======================
#define NT1 8
__global__ __launch_bounds__(256) void k_node1(
    const int* __restrict__ x, const float* __restrict__ emb,
    const float* __restrict__ Wl, const float* __restrict__ bl,
    const float* __restrict__ Wr, const float* __restrict__ br,
    u16* __restrict__ xl, u16* __restrict__ xr)
{
    __shared__ u16 wls[EMB * F1];
    __shared__ u16 wrs[EMB * F1];
    __shared__ float h0s[NT1 * EMB];
    __shared__ int xs[NT1];
    int tid = threadIdx.x;
    for (int i = tid; i < EMB * F1; i += 256) { wls[i] = f2b(Wl[i]); wrs[i] = f2b(Wr[i]); }
    float blr = bl[tid], brr = br[tid];
    __syncthreads();
    const int ntiles = N_NODES / NT1;   // 6250
    for (int tile = blockIdx.x; tile < ntiles; tile += gridDim.x) {
        int nb = tile * NT1;
        if (tid < NT1) xs[tid] = x[nb + tid];
        __syncthreads();
        for (int i = tid; i < NT1 * EMB; i += 256) {
            int nn = i / EMB, k = i - nn * EMB;
            h0s[i] = emb[(size_t)xs[nn] * EMB + k];
        }
        __syncthreads();
        float accl[NT1], accr[NT1];
        #pragma unroll
        for (int n = 0; n < NT1; n++) { accl[n] = blr; accr[n] = brr; }
        for (int k = 0; k < EMB; k++) {
            float wl_ = b2f(wls[k * F1 + tid]);
            float wr_ = b2f(wrs[k * F1 + tid]);
            #pragma unroll
            for (int n = 0; n < NT1; n++) {
                float h = h0s[n * EMB + k];
                accl[n] += h * wl_;
                accr[n] += h * wr_;
            }
        }
        #pragma unroll
        for (int n = 0; n < NT1; n++) {
            xl[(size_t)(nb + n) * F1 + tid] = f2b(accl[n]);
            xr[(size_t)(nb + n) * F1 + tid] = f2b(accr[n]);
        }
        __syncthreads();
    }
}

// ======================= conv1 fused: fp32 fallback =======================
__global__ __launch_bounds__(256) void k_fused1_f(
    const int* __restrict__ rowptr, const int2* __restrict__ epk,
    const float* __restrict__ ea, const u16* __restrict__ xl, const u16* __restrict__ xr,
    const float* __restrict__ We, const float* __restrict__ att, const float* __restrict__ bias,
    float* __restrict__ out, float* __restrict__ Spart)
{
    int node = blockIdx.x;
    int tid = threadIdx.x;
    int h = tid >> 6, lane = tid & 63;
    float weR[EDIM];
    #pragma unroll
    for (int k = 0; k < EDIM; k++) weR[k] = We[k * F1 + tid];
    float attR = att[tid];
    float xr_d = b2f(xr[(size_t)node * F1 + tid]);
    int beg = rowptr[node], end = rowptr[node + 1];
    float m = -1e30f, acc = 0.f, dtot = 0.f;
    for (int j = beg; j < end; j++) {
        int2 p = epk[j];
        int e = __builtin_amdgcn_readfirstlane(p.x);
        int s = __builtin_amdgcn_readfirstlane(p.y);
        const float4* er4 = (const float4*)(ea + (size_t)e * EDIM);   // 112B row, 16B aligned
        float xl_s = b2f(xl[(size_t)s * F1 + tid]);
        float a0 = 0, a1 = 0;
        #pragma unroll
        for (int q = 0; q < 7; q++) {
            float4 v4 = er4[q];
            a0 += v4.x * weR[4 * q]     + v4.z * weR[4 * q + 2];
            a1 += v4.y * weR[4 * q + 1] + v4.w * weR[4 * q + 3];
        }
        float v = lrelu(xl_s + xr_d + a0 + a1) * attR;
        #pragma unroll
        for (int off = 32; off; off >>= 1) v += __shfl_xor(v, off);
        float mn = fmaxf(m, v);
        float scale = __expf(m - mn);
        float p_ = __expf(v - mn);
        acc  = acc  * scale + p_ * xl_s;
        dtot = dtot * scale + p_;
        m = mn;
    }
    float o = ((end > beg) ? acc / (dtot + EPS_SM) : 0.f) + bias[tid];
    out[(size_t)node * F1 + tid] = o;
    float s1 = o, s2 = o * o;
    #pragma unroll
    for (int off = 32; off; off >>= 1) { s1 += __shfl_xor(s1, off); s2 += __shfl_xor(s2, off); }
    __shared__ float ls1[4], ls2[4];
    if (lane == 0) { ls1[h] = s1; ls2[h] = s2; }
    __syncthreads();
    if (tid == 0) {
        Spart[(size_t)node * 2]     = ls1[0] + ls1[1] + ls1[2] + ls1[3];
        Spart[(size_t)node * 2 + 1] = ls2[0] + ls2[1] + ls2[2] + ls2[3];
    }
}

#if HAS_FDOT2
// ======================= conv1 fused: f16 dot2 =======================
__global__ __launch_bounds__(256) void k_fused1_h(
    const int* __restrict__ rowptr, const int2* __restrict__ epk,
    const _Float16* __restrict__ eah, const u16* __restrict__ xl, const u16* __restrict__ xr,
    const float* __restrict__ We, const float* __restrict__ att, const float* __restrict__ bias,
    float* __restrict__ out, float* __restrict__ Spart)
{
    int node = blockIdx.x;
    int tid = threadIdx.x;
    int h = tid >> 6, lane = tid & 63;
    h2 weH[14];
    #pragma unroll
    for (int k2 = 0; k2 < 14; k2++)
        weH[k2] = h2{(_Float16)We[(2 * k2) * F1 + tid], (_Float16)We[(2 * k2 + 1) * F1 + tid]};
    float attR = att[tid];
    float xr_d = b2f(xr[(size_t)node * F1 + tid]);
    int beg = rowptr[node], end = rowptr[node + 1];
    float m = -1e30f, acc = 0.f, dtot = 0.f;
    for (int j = beg; j < end; j++) {
        int2 p = epk[j];
        int e = __builtin_amdgcn_readfirstlane(p.x);
        int s = __builtin_amdgcn_readfirstlane(p.y);
        const uint4* er4 = (const uint4*)(eah + (size_t)e * 32);  // 64B-aligned padded row
        uint4 q0 = er4[0], q1 = er4[1], q2 = er4[2];
        uint2 q3 = *(const uint2*)(er4 + 3);
        float xl_s = b2f(xl[(size_t)s * F1 + tid]);
        float a0 = 0, a1 = 0;
        a0 = __builtin_amdgcn_fdot2(__builtin_bit_cast(h2, q0.x), weH[0],  a0, false);
        a1 = __builtin_amdgcn_fdot2(__builtin_bit_cast(h2, q0.y), weH[1],  a1, false);
        a0 = __builtin_amdgcn_fdot2(__builtin_bit_cast(h2, q0.z), weH[2],  a0, false);
        a1 = __builtin_amdgcn_fdot2(__builtin_bit_cast(h2, q0.w), weH[3],  a1, false);
        a0 = __builtin_amdgcn_fdot2(__builtin_bit_cast(h2, q1.x), weH[4],  a0, false);
        a1 = __builtin_amdgcn_fdot2(__builtin_bit_cast(h2, q1.y), weH[5],  a1, false);
        a0 = __builtin_amdgcn_fdot2(__builtin_bit_cast(h2, q1.z), weH[6],  a0, false);
        a1 = __builtin_amdgcn_fdot2(__builtin_bit_cast(h2, q1.w), weH[7],  a1, false);
        a0 = __builtin_amdgcn_fdot2(__builtin_bit_cast(h2, q2.x), weH[8],  a0, false);
        a1 = __builtin_amdgcn_fdot2(__builtin_bit_cast(h2, q2.y), weH[9],  a1, false);
        a0 = __builtin_amdgcn_fdot2(__builtin_bit_cast(h2, q2.z), weH[10], a0, false);
        a1 = __builtin_amdgcn_fdot2(__builtin_bit_cast(h2, q2.w), weH[11], a1, false);
        a0 = __builtin_amdgcn_fdot2(__builtin_bit_cast(h2, q3.x), weH[12], a0, false);
        a1 = __builtin_amdgcn_fdot2(__builtin_bit_cast(h2, q3.y), weH[13], a1, false);
        float v = lrelu(xl_s + xr_d + a0 + a1) * attR;
        #pragma unroll
        for (int off = 32; off; off >>= 1) v += __shfl_xor(v, off);
        float mn = fmaxf(m, v);
        float scale = __expf(m - mn);
        float p_ = __expf(v - mn);
        acc  = acc  * scale + p_ * xl_s;
        dtot = dtot * scale + p_;
        m = mn;
    }
    float o = ((end > beg) ? acc / (dtot + EPS_SM) : 0.f) + bias[tid];
    out[(size_t)node * F1 + tid] = o;
    float s1 = o, s2 = o * o;
    #pragma unroll
    for (int off = 32; off; off >>= 1) { s1 += __shfl_xor(s1, off); s2 += __shfl_xor(s2, off); }
    __shared__ float ls1[4], ls2[4];
    if (lane == 0) { ls1[h] = s1; ls2[h] = s2; }
    __syncthreads();
    if (tid == 0) {
        Spart[(size_t)node * 2]     = ls1[0] + ls1[1] + ls1[2] + ls1[3];
        Spart[(size_t)node * 2 + 1] = ls2[0] + ls2[1] + ls2[2] + ls2[3];
    }
}
#endif

// ======================= LayerNorm apply (+ReLU) =======================
__global__ void k_ln_apply_relu(
    float* v, const float* __restrict__ w, const float* __restrict__ b,
    const float* __restrict__ S, int M, int C)
{
    int i = blockIdx.x * blockDim.x + threadIdx.x;
    if (i >= M) return;
    float mu = S[0] / (float)M;
    float var = S[1] / (float)M - mu * mu;
    float inv = 1.f / (sqrtf(fmaxf(var, 0.f)) + EPS_LN);
    int c = i % C;
    float y = (v[i] - mu) * inv * w[c] + b[c];
    v[i] = fmaxf(y, 0.f);
}

__global__ void k_ln_out(
    const float* __restrict__ v, const float* __restrict__ w, const float* __restrict__ b,
    const float* __restrict__ S, int M, int C, float* __restrict__ out)
{
    int i = blockIdx.x * blockDim.x + threadIdx.x;
    if (i >= M) return;
    float mu = S[0] / (float)M;
    float var = S[1] / (float)M - mu * mu;
    float inv = 1.f / (sqrtf(fmaxf(var, 0.f)) + EPS_LN);
    int c = i % C;
    out[i] = (v[i] - mu) * inv * w[c] + b[c];
}

// ======================= conv2 node transform =======================
#define NT2 16
__global__ __launch_bounds__(256) void k_node2(
    const float* __restrict__ h, const float* __restrict__ Wl, const float* __restrict__ bl,
    const float* __restrict__ Wr, const float* __restrict__ br,
    float* __restrict__ xl, float* __restrict__ xr)
{
    __shared__ u16 wls[F1 * OUTD];
    __shared__ u16 wrs[F1 * OUTD];
    __shared__ float hs[NT2 * F1];
    int tid = threadIdx.x;
    int w = tid >> 6, lane = tid & 63;
    for (int i = tid; i < F1 * OUTD; i += 256) { wls[i] = f2b(Wl[i]); wrs[i] = f2b(Wr[i]); }
    float blr = (lane < OUTD) ? bl[lane] : 0.f;
    float brr = (lane < OUTD) ? br[lane] : 0.f;
    __syncthreads();
    const int ntiles = N_NODES / NT2;   // 3125
    for (int tile = blockIdx.x; tile < ntiles; tile += gridDim.x) {
        int nb = tile * NT2;
        for (int i = tid; i < NT2 * F1; i += 256) hs[i] = h[(size_t)nb * F1 + i];
        __syncthreads();
        if (lane < OUTD) {
            float accl[4] = {blr, blr, blr, blr};
            float accr[4] = {brr, brr, brr, brr};
            int nl = w * 4;
            for (int k = 0; k < F1; k++) {
                float wl_ = b2f(wls[k * OUTD + lane]);
                float wr_ = b2f(wrs[k * OUTD + lane]);
                #pragma unroll
                for (int n = 0; n < 4; n++) {
                    float hv = hs[(nl + n) * F1 + k];
                    accl[n] += hv * wl_;
                    accr[n] += hv * wr_;
                }
            }
            #pragma unroll
            for (int n = 0; n < 4; n++) {
                xl[(size_t)(nb + nl + n) * OUTD + lane] = accl[n];
                xr[(size_t)(nb + nl + n) * OUTD + lane] = accr[n];
            }
        }
        __syncthreads();
    }
}

// ======================= conv2 fused: fp32 fallback =======================
__global__ __launch_bounds__(256) void k_fused2_f(
    const int* __restrict__ rowptr, const int2* __restrict__ epk,
    const float* __restrict__ ea, const float* __restrict__ xl, const float* __restrict__ xr,
    const float* __restrict__ We, const float* __restrict__ att, const float* __restrict__ bias,
    float* __restrict__ out, float* __restrict__ Spart)
{
    int w = threadIdx.x >> 6, lane = threadIdx.x & 63;
    int node = blockIdx.x * 4 + w;
    bool col = lane < OUTD;
    float weR[EDIM];
    #pragma unroll
    for (int k = 0; k < EDIM; k++) weR[k] = col ? We[k * OUTD + lane] : 0.f;
    float attR = col ? att[lane] : 0.f;
    float xr_d = col ? xr[(size_t)node * OUTD + lane] : 0.f;
    int beg = rowptr[node], end = rowptr[node + 1];
    float m = -1e30f, acc = 0.f, dtot = 0.f;
    for (int j = beg; j < end; j++) {
        int2 p = epk[j];
        int e = __builtin_amdgcn_readfirstlane(p.x);
        int s = __builtin_amdgcn_readfirstlane(p.y);
        const float4* er4 = (const float4*)(ea + (size_t)e * EDIM);
        float xl_s = col ? xl[(size_t)s * OUTD + lane] : 0.f;
        float a0 = 0, a1 = 0;
        #pragma unroll
        for (int q = 0; q < 7; q++) {
            float4 v4 = er4[q];
            a0 += v4.x * weR[4 * q]     + v4.z * weR[4 * q + 2];
            a1 += v4.y * weR[4 * q + 1] + v4.w * weR[4 * q + 3];
        }
        float v = col ? lrelu(xl_s + xr_d + a0 + a1) * attR : 0.f;
        #pragma unroll
        for (int off = 32; off; off >>= 1) v += __shfl_xor(v, off);
        float mn = fmaxf(m, v);
        float scale = __expf(m - mn);
        float p_ = __expf(v - mn);
        acc  = acc  * scale + p_ * xl_s;
        dtot = dtot * scale + p_;
        m = mn;
    }
    float s1 = 0.f, s2 = 0.f;
    if (col) {
        float o = ((end > beg) ? acc / (dtot + EPS_SM) : 0.f) + bias[lane];
        out[(size_t)node * OUTD + lane] = o;
        s1 = o; s2 = o * o;
    }
    #pragma unroll
    for (int off = 32; off; off >>= 1) { s1 += __shfl_xor(s1, off); s2 += __shfl_xor(s2, off); }
    __shared__ float ls1[4], ls2[4];
    if (lane == 0) { ls1[w] = s1; ls2[w] = s2; }
    __syncthreads();
    if (threadIdx.x == 0) {
        Spart[(size_t)blockIdx.x * 2]     = ls1[0] + ls1[1] + ls1[2] + ls1[3];
        Spart[(size_t)blockIdx.x * 2 + 1] = ls2[0] + ls2[1] + ls2[2] + ls2[3];
    }
}

#if HAS_FDOT2
// ======================= conv2 fused: f16 dot2 =======================
__global__ __launch_bounds__(256) void k_fused2_h(
    const int* __restrict__ rowptr, const int2* __restrict__ epk,
    const _Float16* __restrict__ eah, const float* __restrict__ xl, const float* __restrict__ xr,
    const float* __restrict__ We, const float* __restrict__ att, const float* __restrict__ bias,
    float* __restrict__ out, float* __restrict__ Spart)
{
    int w = threadIdx.x >> 6, lane = threadIdx.x & 63;
    int node = blockIdx.x * 4 + w;
    bool col = lane < OUTD;
    h2 weH[14];
    #pragma unroll
    for (int k2 = 0; k2 < 14; k2++)
        weH[k2] = col ? h2{(_Float16)We[(2 * k2) * OUTD + lane], (_Float16)We[(2 * k2 + 1) * OUTD + lane]}
                      : h2{(_Float16)0.f, (_Float16)0.f};
    float attR = col ? att[lane] : 0.f;
    float xr_d = col ? xr[(size_t)node * OUTD + lane] : 0.f;
    int beg = rowptr[node], end = rowptr[node + 1];
    float m = -1e30f, acc = 0.f, dtot = 0.f;
    for (int j = beg; j < end; j++) {
        int2 p = epk[j];
        int e = __builtin_amdgcn_readfirstlane(p.x);
        int s = __builtin_amdgcn_readfirstlane(p.y);
        const uint4* er4 = (const uint4*)(eah + (size_t)e * 32);
        uint4 q0 = er4[0], q1 = er4[1], q2 = er4[2];
        uint2 q3 = *(const uint2*)(er4 + 3);
        float xl_s = col ? xl[(size_t)s * OUTD + lane] : 0.f;
        float a0 = 0, a1 = 0;
        a0 = __builtin_amdgcn_fdot2(__builtin_bit_cast(h2, q0.x), weH[0],  a0, false);
        a1 = __builtin_amdgcn_fdot2(__builtin_bit_cast(h2, q0.y), weH[1],  a1, false);
        a0 = __builtin_amdgcn_fdot2(__builtin_bit_cast(h2, q0.z), weH[2],  a0, false);
        a1 = __builtin_amdgcn_fdot2(__builtin_bit_cast(h2, q0.w), weH[3],  a1, false);
        a0 = __builtin_amdgcn_fdot2(__builtin_bit_cast(h2, q1.x), weH[4],  a0, false);
        a1 = __builtin_amdgcn_fdot2(__builtin_bit_cast(h2, q1.y), weH[5],  a1, false);
        a0 = __builtin_amdgcn_fdot2(__builtin_bit_cast(h2, q1.z), weH[6],  a0, false);
        a1 = __builtin_amdgcn_fdot2(__builtin_bit_cast(h2, q1.w), weH[7],  a1, false);
        a0 = __builtin_amdgcn_fdot2(__builtin_bit_cast(h2, q2.x), weH[8],  a0, false);
        a1 = __builtin_amdgcn_fdot2(__builtin_bit_cast(h2, q2.y), weH[9],  a1, false);
        a0 = __builtin_amdgcn_fdot2(__builtin_bit_cast(h2, q2.z), weH[10], a0, false);
        a1 = __builtin_amdgcn_fdot2(__builtin_bit_cast(h2, q2.w), weH[11], a1, false);
        a0 = __builtin_amdgcn_fdot2(__builtin_bit_cast(h2, q3.x), weH[12], a0, false);
        a1 = __builtin_amdgcn_fdot2(__builtin_bit_cast(h2, q3.y), weH[13], a1, false);
        float v = col ? lrelu(xl_s + xr_d + a0 + a1) * attR : 0.f;
        #pragma unroll
        for (int off = 32; off; off >>= 1) v += __shfl_xor(v, off);
        float mn = fmaxf(m, v);
        float scale = __expf(m - mn);
        float p_ = __expf(v - mn);
        acc  = acc  * scale + p_ * xl_s;
        dtot = dtot * scale + p_;
        m = mn;
    }
    float s1 = 0.f, s2 = 0.f;
    if (col) {
        float o = ((end > beg) ? acc / (dtot + EPS_SM) : 0.f) + bias[lane];
        out[(size_t)node * OUTD + lane] = o;
        s1 = o; s2 = o * o;
    }
    #pragma unroll
    for (int off = 32; off; off >>= 1) { s1 += __shfl_xor(s1, off); s2 += __shfl_xor(s2, off); }
    __shared__ float ls1[4], ls2[4];
    if (lane == 0) { ls1[w] = s1; ls2[w] = s2; }
    __syncthreads();
    if (threadIdx.x == 0) {
        Spart[(size_t)blockIdx.x * 2]     = ls1[0] + ls1[1] + ls1[2] + ls1[3];
        Spart[(size_t)blockIdx.x * 2 + 1] = ls2[0] + ls2[1] + ls2[2] + ls2[3];
    }
}
#endif

extern "C" void kernel_launch(void* const* d_in, const int* in_sizes, int n_in,
                              void* d_out, int out_size, void* d_ws, size_t ws_size,
                              hipStream_t stream)
{
    const int*   x    = (const int*)d_in[0];
    const int*   ei   = (const int*)d_in[1];
    const int*   srcA = ei;
    const int*   dstA = ei + N_EDGES;
    const float* ea   = (const float*)d_in[2];
    const float* emb  = (const float*)d_in[3];
    const float* Wl1  = (const float*)d_in[4];
    const float* bl1  = (const float*)d_in[5];
    const float* Wr1  = (const float*)d_in[6];
    const float* br1  = (const float*)d_in[7];
    const float* We1  = (const float*)d_in[8];
    const float* att1 = (const float*)d_in[9];
    const float* bias1= (const float*)d_in[10];
    const float* ln1w = (const float*)d_in[11];
    const float* ln1b = (const float*)d_in[12];
    const float* Wl2  = (const float*)d_in[13];
    const float* bl2  = (const float*)d_in[14];
    const float* Wr2  = (const float*)d_in[15];
    const float* br2  = (const float*)d_in[16];
    const float* We2  = (const float*)d_in[17];
    const float* att2 = (const float*)d_in[18];
    const float* bias2= (const float*)d_in[19];
    const float* ln2w = (const float*)d_in[20];
    const float* ln2b = (const float*)d_in[21];

    // workspace layout (float offsets); base peak 26.87M floats = 107.5MB,
    // +8M floats (eah, f16 path) = 139.5MB — used only if ws_size allows.
    float* W = (float*)d_ws;
    u16*   xl1b    = (u16*)W;                      // [0, 6.4M)
    u16*   xr1b    = (u16*)(W + 6400000);          // [6.4M, 12.8M)
    float* out1    = W + 12800000;                 // [12.8M, 25.6M)  (h1 in place)
    int2*  epk     = (int2*)(W + 25600000);        // [25.6M, 26.6M)
    int*   rowptr  = (int*)(W + 26600000);         // N+1
    int*   cnt     = (int*)(W + 26660000);         // N
    int*   cursor  = (int*)(W + 26710000);         // N
    float* Spart   = W + 26760000;                 // 2*N
    float* S       = W + 26870000;                 // 4
    _Float16* eah  = (_Float16*)(W + 26880000);    // E*32 halves = 8M floats [26.88M, 34.88M)
    // reuse (liveness-checked):
    float* xl2     = W;                            // [0, 2.5M)    xl1b dead after fused1
    float* xr2     = W + 2500000;                  // [2.5M, 5M)
    float* out2    = W + 6400000;                  // [6.4M, 8.9M) xr1b dead after fused1
    float* h1      = out1;

    bool useh = false;
#if HAS_FDOT2
    useh = ws_size >= (size_t)34880004 * sizeof(float);
#endif

    hipMemsetAsync(cnt, 0, N_NODES * sizeof(int), stream);
    hipMemsetAsync(cursor, 0, N_NODES * sizeof(int), stream);
    hipMemsetAsync(S, 0, 4 * sizeof(float), stream);

    // CSR build
    k_hist<<<(N_EDGES + 255) / 256, 256, 0, stream>>>(dstA, cnt);
    k_scan<<<1, 1024, 0, stream>>>(cnt, rowptr);
    k_scatter<<<(N_EDGES + 255) / 256, 256, 0, stream>>>(srcA, dstA, rowptr, cursor, epk);

    // conv1
    k_node1<<<1024, 256, 0, stream>>>(x, emb, Wl1, bl1, Wr1, br1, xl1b, xr1b);
#if HAS_FDOT2
    if (useh) {
        k_tohalf<<<(N_EDGES * 7 + 255) / 256, 256, 0, stream>>>(ea, eah);
        k_fused1_h<<<N_NODES, 256, 0, stream>>>(rowptr, epk, eah, xl1b, xr1b, We1, att1, bias1, out1, Spart);
    } else
#endif
    {
        k_fused1_f<<<N_NODES, 256, 0, stream>>>(rowptr, epk, ea, xl1b, xr1b, We1, att1, bias1, out1, Spart);
    }
    k_sumpart<<<32, 256, 0, stream>>>(Spart, N_NODES, S);
    k_ln_apply_relu<<<(N_NODES * F1 + 255) / 256, 256, 0, stream>>>(out1, ln1w, ln1b, S, N_NODES * F1, F1);

    // conv2
    k_node2<<<1024, 256, 0, stream>>>(h1, Wl2, bl2, Wr2, br2, xl2, xr2);
#if HAS_FDOT2
    if (useh) {
        k_fused2_h<<<N_NODES / 4, 256, 0, stream>>>(rowptr, epk, eah, xl2, xr2, We2, att2, bias2, out2, Spart);
    } else
#endif
    {
        k_fused2_f<<<N_NODES / 4, 256, 0, stream>>>(rowptr, epk, ea, xl2, xr2, We2, att2, bias2, out2, Spart);
    }
    k_sumpart<<<32, 256, 0, stream>>>(Spart, N_NODES / 4, S + 2);
    k_ln_out<<<(N_NODES * OUTD + 255) / 256, 256, 0, stream>>>(out2, ln2w, ln2b, S + 2, N_NODES * OUTD, OUTD, (float*)d_out);
}